// Round 2
// baseline (1377.156 us; speedup 1.0000x reference)
//
#include <hip/hip_runtime.h>
#include <math.h>

constexpr int DIM = 64;

// ---------------------------------------------------------------------------
// Kernel A: normalize indptr (int64 or int32 on disk) -> int32 in workspace.
// Detection: if the data is int64, entry[1] (= first inner breakpoint) is in
// [0, n_cuts]. If it is int32, the int64 view of [1] combines indptr[2] and
// indptr[3] -> (value | next<<32), which exceeds n_cuts unless both are ~0
// (probability ~0 for sorted random breakpoints).
// ---------------------------------------------------------------------------
__global__ void convert_indptr_kernel(const void* __restrict__ indptr_raw,
                                      int* __restrict__ indptr32,
                                      int n_entries, long long n_cuts) {
    const long long* p64 = (const long long*)indptr_raw;
    const int*       p32 = (const int*)indptr_raw;
    long long probe = p64[1];
    bool is64 = (probe >= 0 && probe <= n_cuts);
    int i = blockIdx.x * blockDim.x + threadIdx.x;
    if (i < n_entries) {
        indptr32[i] = is64 ? (int)p64[i] : p32[i];
    }
}

// ---------------------------------------------------------------------------
// Kernel B: one wave (64 lanes) per segment. Per iteration the wave reads
// 4 consecutive rows x 64 dims = 1 KiB contiguous (float4 per lane).
// sub = lane>>4 selects the row within the group of 4; (lane&15)*4 selects
// the dim quad. After the loop, shfl_xor(16)+shfl_xor(32) folds the four
// row-groups; lanes 0..15 hold the final 64-dim segment sum as float4.
// Applies ve = log1p(sum/lib[c]) - 2 and writes the first half (dims 0..63)
// of the output row (c, v, :128).
// ---------------------------------------------------------------------------
__global__ __launch_bounds__(256) void seg_sum_kernel(
    const float* __restrict__ emb,
    const int* __restrict__ indptr,
    const float* __restrict__ lib,
    float* __restrict__ out,
    int n_seg, int n_variants) {

    int wave = (int)((blockIdx.x * blockDim.x + threadIdx.x) >> 6);
    int lane = threadIdx.x & 63;
    if (wave >= n_seg) return;

    int start = indptr[wave];
    int end   = indptr[wave + 1];

    int sub = lane >> 4;          // 0..3 : row offset within group of 4
    int dg  = (lane & 15) << 2;   // dim quad base: 0,4,...,60

    float4 acc = make_float4(0.f, 0.f, 0.f, 0.f);
    for (int r = start + sub; r < end; r += 4) {
        const float4 v = *reinterpret_cast<const float4*>(
            emb + (size_t)r * DIM + dg);
        acc.x += v.x; acc.y += v.y; acc.z += v.z; acc.w += v.w;
    }

    // fold the 4 row-groups (lanes l, l+16, l+32, l+48 share a dim quad)
    acc.x += __shfl_xor(acc.x, 16, 64);
    acc.y += __shfl_xor(acc.y, 16, 64);
    acc.z += __shfl_xor(acc.z, 16, 64);
    acc.w += __shfl_xor(acc.w, 16, 64);
    acc.x += __shfl_xor(acc.x, 32, 64);
    acc.y += __shfl_xor(acc.y, 32, 64);
    acc.z += __shfl_xor(acc.z, 32, 64);
    acc.w += __shfl_xor(acc.w, 32, 64);

    if (sub == 0) {
        int c = wave / n_variants;
        int v = wave - c * n_variants;
        float libc_v = lib[c];
        float4 y;
        y.x = log1pf(acc.x / libc_v) - 2.0f;
        y.y = log1pf(acc.y / libc_v) - 2.0f;
        y.z = log1pf(acc.z / libc_v) - 2.0f;
        y.w = log1pf(acc.w / libc_v) - 2.0f;
        float* dst = out + ((size_t)wave) * (2 * DIM) + dg;
        *reinterpret_cast<float4*>(dst) = y;
    }
}

// ---------------------------------------------------------------------------
// Kernel C: one thread per (variant, dim). Two-pass mean / std(ddof=1) over
// the n_clusters axis, reading the ve half of out (written by kernel B) and
// writing the rel half. Two-pass avoids cancellation (ve ~ -2 +- 1e-4).
// ---------------------------------------------------------------------------
__global__ __launch_bounds__(256) void norm_kernel(
    float* __restrict__ out, int n_clusters, int n_variants) {

    int p = blockIdx.x * blockDim.x + threadIdx.x;
    int total = n_variants * DIM;
    if (p >= total) return;

    int v = p >> 6;      // DIM == 64
    int d = p & 63;

    size_t base    = (size_t)v * (2 * DIM) + d;
    size_t cstride = (size_t)n_variants * (2 * DIM);

    float sum = 0.f;
    for (int c = 0; c < n_clusters; ++c)
        sum += out[(size_t)c * cstride + base];
    float mean = sum / (float)n_clusters;

    float var = 0.f;
    for (int c = 0; c < n_clusters; ++c) {
        float dlt = out[(size_t)c * cstride + base] - mean;
        var += dlt * dlt;
    }
    float stdv  = sqrtf(var / (float)(n_clusters - 1));
    float denom = stdv + 1e-5f;

    for (int c = 0; c < n_clusters; ++c) {
        float x = out[(size_t)c * cstride + base];
        out[(size_t)c * cstride + base + DIM] = (x - mean) / denom;
    }
}

extern "C" void kernel_launch(void* const* d_in, const int* in_sizes, int n_in,
                              void* d_out, int out_size, void* d_ws, size_t ws_size,
                              hipStream_t stream) {
    const float* emb        = (const float*)d_in[0];
    const float* lib        = (const float*)d_in[1];
    const void*  indptr_raw = d_in[2];

    int n_clusters = in_sizes[1];
    int n_entries  = in_sizes[2];
    int n_seg      = n_entries - 1;
    int n_variants = n_seg / n_clusters;
    long long n_cuts = (long long)in_sizes[0] / DIM;

    int*   indptr32 = (int*)d_ws;
    float* out      = (float*)d_out;

    // A: indptr dtype-normalize into workspace
    convert_indptr_kernel<<<(n_entries + 255) / 256, 256, 0, stream>>>(
        indptr_raw, indptr32, n_entries, n_cuts);

    // B: per-segment sum + log1p transform, writes ve half of out
    int nblocks = (n_seg + 3) / 4;  // 4 waves (256 threads) per block
    seg_sum_kernel<<<nblocks, 256, 0, stream>>>(
        emb, indptr32, lib, out, n_seg, n_variants);

    // C: cluster-axis normalize, writes rel half of out
    int total = n_variants * DIM;
    norm_kernel<<<(total + 255) / 256, 256, 0, stream>>>(
        out, n_clusters, n_variants);
}